// Round 9
// baseline (330.323 us; speedup 1.0000x reference)
//
#include <hip/hip_runtime.h>
#include <hip/hip_fp8.h>
#include <hip/hip_bf16.h>

// Problem constants: M=8192, H=4096 (=K=N), GROUP=128.
#define MDIM 8192
#define HDIM 4096
#define NKT 64  // K tiles of 64

typedef float f32x4 __attribute__((ext_vector_type(4)));
typedef short bf16x8 __attribute__((ext_vector_type(8)));
typedef unsigned short u16x4 __attribute__((ext_vector_type(4)));

__device__ inline void gload_lds16(const void* g, void* l) {
  __builtin_amdgcn_global_load_lds(
      (const __attribute__((address_space(1))) void*)g,
      (__attribute__((address_space(3))) void*)l, 16, 0, 0);
}

__device__ inline unsigned short f2bf(float f) {
  __hip_bfloat16 h = __float2bfloat16(f);
  return *reinterpret_cast<unsigned short*>(&h);
}

// ---------------------------------------------------------------------------
// Kernel 1: y = silu(gate)*up; per-(1,128) fp8 group quant; emit y_dq as bf16.
// ---------------------------------------------------------------------------
__global__ __launch_bounds__(256) void silu_quant_kernel(
    const float* __restrict__ x, unsigned short* __restrict__ yb) {
  const int m = blockIdx.x;
  const int t = threadIdx.x;
  const int g = t >> 3;   // group 0..31
  const int i = t & 7;    // lane-in-group
  const float* xr = x + (size_t)m * (2 * HDIM);

  float v[16];
  float amax = 0.f;
#pragma unroll
  for (int j = 0; j < 4; ++j) {
    const int off = g * 128 + j * 32 + i * 4;
    f32x4 gate = *(const f32x4*)(xr + off);
    f32x4 up = *(const f32x4*)(xr + HDIM + off);
#pragma unroll
    for (int c = 0; c < 4; ++c) {
      float gg = gate[c];
      float s = gg / (1.f + expf(-gg));
      float val = s * up[c];
      v[j * 4 + c] = val;
      amax = fmaxf(amax, fabsf(val));
    }
  }
#pragma unroll
  for (int d = 1; d < 8; d <<= 1) amax = fmaxf(amax, __shfl_xor(amax, d, 64));
  const float scale = fmaxf(amax, 1e-12f) / 448.0f;

#pragma unroll
  for (int j = 0; j < 4; ++j) {
    u16x4 pk;
#pragma unroll
    for (int c = 0; c < 4; ++c) {
      __hip_fp8_e4m3 qv(v[j * 4 + c] / scale);  // RNE onto e4m3fn grid
      pk[c] = f2bf((float)qv * scale);          // dequantized, to bf16
    }
    *(u16x4*)(yb + (size_t)m * HDIM + g * 128 + j * 32 + i * 4) = pk;
  }
}

// ---------------------------------------------------------------------------
// Kernel 2: wt[n][k] = bf16( w_q[k][n] * wscale[k/128][n/128] )  (transposed)
// ---------------------------------------------------------------------------
__global__ __launch_bounds__(256) void wconv_kernel(
    const float* __restrict__ w, const float* __restrict__ wsc,
    unsigned short* __restrict__ wt) {
  __shared__ unsigned short tile[64][66];
  const int t = threadIdx.x;
  const int n0 = (blockIdx.x & 63) * 64;
  const int k0 = (blockIdx.x >> 6) * 64;
  const float ws = wsc[(k0 >> 7) * 32 + (n0 >> 7)];
  {
    const int r = t >> 4;
    const int c4 = (t & 15) << 2;
#pragma unroll
    for (int j = 0; j < 4; ++j) {
      const int kr = r + j * 16;
      f32x4 vv = *(const f32x4*)(w + (size_t)(k0 + kr) * HDIM + n0 + c4);
#pragma unroll
      for (int c = 0; c < 4; ++c) tile[kr][c4 + c] = f2bf(vv[c] * ws);
    }
  }
  __syncthreads();
  {
    const int n = t >> 4;
    const int k4 = (t & 15) << 2;
#pragma unroll
    for (int j = 0; j < 4; ++j) {
      const int nn = n + j * 16;
      u16x4 pk;
#pragma unroll
      for (int c = 0; c < 4; ++c) pk[c] = tile[k4 + c][nn];
      *(u16x4*)(wt + (size_t)(n0 + nn) * HDIM + k0 + k4) = pk;
    }
  }
}

// ---------------------------------------------------------------------------
// Kernel 3: bf16 GEMM, 256x256 tile, BK=64, 8 waves (2Mx4N, 128x64 each).
// m201-style phase-locked schedule: per phase
//   { ds_read quadrant subtile ; stage ; SBAR ; lgkm0 ; prio1 16xMFMA prio0 ;
//     [P4: vmcnt(0)] ; SBAR }
// Stage ledger (provably race-free, 2 buffers):
//   P1 stages units 0,1 of T(j+1) -> buf n;  P2 stages units 2,3 -> buf n.
//   buf n's occupant T(j-1) was fully read by end of iter j-1 (lgkm-drained
//   reads + trailing barrier), so writes to n are always safe.
//   vmcnt(0) sits after P4's MFMA: issue-to-wait slack = 2.5-3.5 phases
//   (~2500+ cyc) > loaded HBM/L2 latency -> ~zero stall despite full drain.
// Quadrant order (0,0)(1,0)(1,1)(0,1): reads 12/8/4/0 b128; afr0,bfr1 persist.
// LDS: [256 rows][128B], stored 16B-chunk = chunk ^ (row&7); linear dest +
// pre-swizzled global source + swizzled ds_read (rule 21). Conflict-free
// (r6/r8: SQ_LDS_BANK_CONFLICT = 0).
// ---------------------------------------------------------------------------
#define SCHED0 __builtin_amdgcn_sched_barrier(0)
#define SBAR do { SCHED0; __builtin_amdgcn_s_barrier(); SCHED0; } while (0)
#define VMW0 asm volatile("s_waitcnt vmcnt(0)" ::: "memory")
#define LGKM0 asm volatile("s_waitcnt lgkmcnt(0)" ::: "memory")
#define PRIO1 __builtin_amdgcn_s_setprio(1)
#define PRIO0 __builtin_amdgcn_s_setprio(0)

// half-tile units: 0 = A-lo, 1 = B-lo, 2 = A-hi, 3 = B-hi
#define STAGE_UNIT(bi, kt, u) do {                                          \
    const __hip_bfloat16* gsrc;  unsigned char* ldst;                       \
    if ((u) == 0)      { gsrc = A + (size_t)(m0 + r0) * HDIM;       ldst = As[bi]; }          \
    else if ((u) == 1) { gsrc = B + (size_t)(n0 + r0) * HDIM;       ldst = Bs[bi]; }          \
    else if ((u) == 2) { gsrc = A + (size_t)(m0 + 128 + r0) * HDIM; ldst = As[bi] + 16384; }  \
    else               { gsrc = B + (size_t)(n0 + 128 + r0) * HDIM; ldst = Bs[bi] + 16384; }  \
    gsrc += (size_t)(kt) * 64 + cst * 8;                                    \
    gload_lds16(gsrc, ldst + t * 16);                                       \
    gload_lds16(gsrc + (size_t)64 * HDIM, ldst + 8192 + t * 16);            \
  } while (0)

#define RD_A(c, mh, dst) do { _Pragma("unroll") for (int mi = 0; mi < 4; ++mi) { \
    const int row = wm * 128 + (mh) * 64 + mi * 16 + lrow;                       \
    _Pragma("unroll") for (int kk = 0; kk < 2; ++kk)                             \
      dst[mi][kk] = *(const bf16x8*)(As[c] + row * 128 + (((kk * 4 + lhi) ^ rx) * 16)); \
  } } while (0)

#define RD_B(c, nh, dst) do { _Pragma("unroll") for (int ni = 0; ni < 2; ++ni) { \
    const int row = wn * 64 + (nh) * 32 + ni * 16 + lrow;                        \
    _Pragma("unroll") for (int kk = 0; kk < 2; ++kk)                             \
      dst[ni][kk] = *(const bf16x8*)(Bs[c] + row * 128 + (((kk * 4 + lhi) ^ rx) * 16)); \
  } } while (0)

#define MFMA16(AF, BF, MB, NB) do { _Pragma("unroll") for (int kk = 0; kk < 2; ++kk) \
    _Pragma("unroll") for (int mi = 0; mi < 4; ++mi)                                 \
      _Pragma("unroll") for (int ni = 0; ni < 2; ++ni)                               \
        acc[(MB) + mi][(NB) + ni] = __builtin_amdgcn_mfma_f32_16x16x32_bf16(         \
            AF[mi][kk], BF[ni][kk], acc[(MB) + mi][(NB) + ni], 0, 0, 0);             \
  } while (0)

#define ITER(j, SH) do {                                                     \
    const int c_ = (j) & 1, n_ = c_ ^ 1;                                     \
    /* P1: quadrant (0,0); stage units 0,1 of T(j+1) */                      \
    RD_A(c_, 0, afr0); RD_B(c_, 0, bfr0);                                    \
    if (SH) { STAGE_UNIT(n_, (j) + 1, 0); STAGE_UNIT(n_, (j) + 1, 1); }      \
    SBAR; LGKM0; SCHED0;                                                     \
    PRIO1; MFMA16(afr0, bfr0, 0, 0); PRIO0;                                  \
    SBAR;                                                                    \
    /* P2: quadrant (1,0); stage units 2,3 of T(j+1) */                      \
    RD_A(c_, 1, afr1);                                                       \
    if (SH) { STAGE_UNIT(n_, (j) + 1, 2); STAGE_UNIT(n_, (j) + 1, 3); }      \
    SBAR; LGKM0; SCHED0;                                                     \
    PRIO1; MFMA16(afr1, bfr0, 4, 0); PRIO0;                                  \
    SBAR;                                                                    \
    /* P3: quadrant (1,1) */                                                 \
    RD_B(c_, 1, bfr1);                                                       \
    SBAR; LGKM0; SCHED0;                                                     \
    PRIO1; MFMA16(afr1, bfr1, 4, 2); PRIO0;                                  \
    SBAR;                                                                    \
    /* P4: quadrant (0,1); drain T(j+1) loads (issued >=2.5 phases ago) */   \
    PRIO1; MFMA16(afr0, bfr1, 0, 2); PRIO0;                                  \
    SCHED0; VMW0; SBAR;                                                      \
  } while (0)

__global__ __launch_bounds__(512, 1) void gemm_bf16_kernel(
    const __hip_bfloat16* __restrict__ A,   // y_dq [8192][4096]
    const __hip_bfloat16* __restrict__ B,   // w_dq^T [4096][4096] (n-major)
    float* __restrict__ out) {              // [8192][4096]
  __shared__ __align__(16) unsigned char As[2][32768];
  __shared__ __align__(16) unsigned char Bs[2][32768];

  // XCD-aware swizzle: grid 512 = 32m x 16n tiles; XCD x gets an 8x8 sub-grid.
  const int bid = blockIdx.x;
  const int x = bid & 7, sub = bid >> 3;
  const int mtile = (x >> 1) * 8 + (sub & 7);
  const int ntile = (x & 1) * 8 + (sub >> 3);
  const int m0 = mtile * 256, n0 = ntile * 256;

  const int t = threadIdx.x;
  const int l = t & 63, wid = t >> 6;
  const int wm = wid >> 2, wn = wid & 3;    // 2x4 waves, 128x64 each
  const int lrow = l & 15, lhi = l >> 4;
  const int rx = lrow & 7;

  const int r0 = t >> 3;                    // staging row (0..63)
  const int cst = (t & 7) ^ (r0 & 7);       // pre-swizzled source chunk

  f32x4 acc[8][4];
#pragma unroll
  for (int a = 0; a < 8; ++a)
#pragma unroll
    for (int b = 0; b < 4; ++b) acc[a][b] = (f32x4){0.f, 0.f, 0.f, 0.f};
  bf16x8 afr0[4][2], afr1[4][2], bfr0[2][2], bfr1[2][2];

  // prologue: stage T0 fully into buf 0; one-time full-latency drain
  STAGE_UNIT(0, 0, 0); STAGE_UNIT(0, 0, 1); STAGE_UNIT(0, 0, 2); STAGE_UNIT(0, 0, 3);
  VMW0;
  SBAR;

  for (int j = 0; j < NKT - 1; ++j) ITER(j, 1);
  ITER(NKT - 1, 0);

  // epilogue: C row = lhi*4+r (m), col = lrow (n)
#pragma unroll
  for (int mi = 0; mi < 8; ++mi)
#pragma unroll
    for (int r = 0; r < 4; ++r) {
      const int grow = m0 + wm * 128 + mi * 16 + lhi * 4 + r;
      float* orow = out + (size_t)grow * HDIM + n0 + wn * 64 + lrow;
#pragma unroll
      for (int ni = 0; ni < 4; ++ni) orow[ni * 16] = acc[mi][ni][r];
    }
}

// ---------------------------------------------------------------------------
extern "C" void kernel_launch(void* const* d_in, const int* in_sizes, int n_in,
                              void* d_out, int out_size, void* d_ws, size_t ws_size,
                              hipStream_t stream) {
  const float* x = (const float*)d_in[0];    // [8192][8192]
  const float* wq = (const float*)d_in[1];   // [4096][4096]
  const float* wsc = (const float*)d_in[2];  // [32][32]
  float* out = (float*)d_out;                // [8192][4096]

  unsigned short* yb = (unsigned short*)d_ws;                   // 64 MiB bf16 y_dq
  unsigned short* wt = yb + (size_t)MDIM * HDIM;                // 32 MiB bf16 w_dq^T

  silu_quant_kernel<<<MDIM, 256, 0, stream>>>(x, yb);
  wconv_kernel<<<(HDIM / 64) * (HDIM / 64), 256, 0, stream>>>(wq, wsc, wt);
  gemm_bf16_kernel<<<(MDIM / 256) * (HDIM / 256), 512, 0, stream>>>(
      (const __hip_bfloat16*)yb, (const __hip_bfloat16*)wt, out);
}

// Round 10
// 319.615 us; speedup vs baseline: 1.0335x; 1.0335x over previous
//
#include <hip/hip_runtime.h>
#include <hip/hip_fp8.h>
#include <hip/hip_bf16.h>

// Problem constants: M=8192, H=4096 (=K=N), GROUP=128.
#define MDIM 8192
#define HDIM 4096
#define NKT 64  // K tiles of 64

typedef float f32x4 __attribute__((ext_vector_type(4)));
typedef short bf16x8 __attribute__((ext_vector_type(8)));
typedef unsigned short u16x4 __attribute__((ext_vector_type(4)));

__device__ inline void gload_lds16(const void* g, void* l) {
  __builtin_amdgcn_global_load_lds(
      (const __attribute__((address_space(1))) void*)g,
      (__attribute__((address_space(3))) void*)l, 16, 0, 0);
}

__device__ inline unsigned short f2bf(float f) {
  __hip_bfloat16 h = __float2bfloat16(f);
  return *reinterpret_cast<unsigned short*>(&h);
}

// ---------------------------------------------------------------------------
// Kernel 1: y = silu(gate)*up; per-(1,128) fp8 group quant; emit y_dq as bf16.
// ---------------------------------------------------------------------------
__global__ __launch_bounds__(256) void silu_quant_kernel(
    const float* __restrict__ x, unsigned short* __restrict__ yb) {
  const int m = blockIdx.x;
  const int t = threadIdx.x;
  const int g = t >> 3;   // group 0..31
  const int i = t & 7;    // lane-in-group
  const float* xr = x + (size_t)m * (2 * HDIM);

  float v[16];
  float amax = 0.f;
#pragma unroll
  for (int j = 0; j < 4; ++j) {
    const int off = g * 128 + j * 32 + i * 4;
    f32x4 gate = *(const f32x4*)(xr + off);
    f32x4 up = *(const f32x4*)(xr + HDIM + off);
#pragma unroll
    for (int c = 0; c < 4; ++c) {
      float gg = gate[c];
      float s = gg / (1.f + expf(-gg));
      float val = s * up[c];
      v[j * 4 + c] = val;
      amax = fmaxf(amax, fabsf(val));
    }
  }
#pragma unroll
  for (int d = 1; d < 8; d <<= 1) amax = fmaxf(amax, __shfl_xor(amax, d, 64));
  const float scale = fmaxf(amax, 1e-12f) / 448.0f;

#pragma unroll
  for (int j = 0; j < 4; ++j) {
    u16x4 pk;
#pragma unroll
    for (int c = 0; c < 4; ++c) {
      __hip_fp8_e4m3 qv(v[j * 4 + c] / scale);  // RNE onto e4m3fn grid
      pk[c] = f2bf((float)qv * scale);          // dequantized, to bf16
    }
    *(u16x4*)(yb + (size_t)m * HDIM + g * 128 + j * 32 + i * 4) = pk;
  }
}

// ---------------------------------------------------------------------------
// Kernel 2: wt[n][k] = bf16( w_q[k][n] * wscale[k/128][n/128] )  (transposed)
// ---------------------------------------------------------------------------
__global__ __launch_bounds__(256) void wconv_kernel(
    const float* __restrict__ w, const float* __restrict__ wsc,
    unsigned short* __restrict__ wt) {
  __shared__ unsigned short tile[64][66];
  const int t = threadIdx.x;
  const int n0 = (blockIdx.x & 63) * 64;
  const int k0 = (blockIdx.x >> 6) * 64;
  const float ws = wsc[(k0 >> 7) * 32 + (n0 >> 7)];
  {
    const int r = t >> 4;
    const int c4 = (t & 15) << 2;
#pragma unroll
    for (int j = 0; j < 4; ++j) {
      const int kr = r + j * 16;
      f32x4 vv = *(const f32x4*)(w + (size_t)(k0 + kr) * HDIM + n0 + c4);
#pragma unroll
      for (int c = 0; c < 4; ++c) tile[kr][c4 + c] = f2bf(vv[c] * ws);
    }
  }
  __syncthreads();
  {
    const int n = t >> 4;
    const int k4 = (t & 15) << 2;
#pragma unroll
    for (int j = 0; j < 4; ++j) {
      const int nn = n + j * 16;
      u16x4 pk;
#pragma unroll
      for (int c = 0; c < 4; ++c) pk[c] = tile[k4 + c][nn];
      *(u16x4*)(wt + (size_t)(n0 + nn) * HDIM + k0 + k4) = pk;
    }
  }
}

// ---------------------------------------------------------------------------
// Kernel 3: bf16 GEMM, 256x256 tile, BK=64, 8 waves (2Mx4N, 128x64 each).
// r8 skeleton (4 phases, 2 barriers/iter, NO explicit lgkm before MFMA --
// compiler emits fine-grained lgkmcnt so early MFMAs overlap late ds_reads).
// r10 change: front-loaded stage schedule + vmcnt(4) depth.
// Stage ledger (half-tile units: 0=A-lo,1=B-lo,2=A-hi,3=B-hi; 2 gloads each):
//   invariant at entry of iter j: buf[j&1] = T(j) landed;
//                                 flying = T(j+1).u0,u1 (4 loads) -> buf n.
//   P1: stage T(j+1).u2 -> buf n   (occupant T(j-1) fully read last iter;
//   P2: stage T(j+1).u3 -> buf n    disjoint from in-flight u0/u1 regions)
//   P3: no stage; lgkm0 + barrier  (all reads of buf c done chip-wide)
//   P4: stage T(j+2).u0,u1 -> buf c (safe after P3 barrier);
//       MFMA; vmcnt(4) -> T(j+1)'s 8 oldest landed, T(j+2).u0,u1 fly; barrier
// Min issue-to-wait slack ~2 phases; u0/u1 slack ~4 phases.
// Quadrant order (0,0)(1,0)(1,1)(0,1): reads 12/8/4/0 b128; afr0,bfr1 persist.
// LDS: [256 rows][128B], stored 16B-chunk = chunk ^ (row&7); linear dest +
// pre-swizzled global source + swizzled ds_read (rule 21). Conflict-free
// (r6/r8: SQ_LDS_BANK_CONFLICT = 0).
// ---------------------------------------------------------------------------
#define SCHED0 __builtin_amdgcn_sched_barrier(0)
#define SBAR do { SCHED0; __builtin_amdgcn_s_barrier(); SCHED0; } while (0)
#define VMW(n) asm volatile("s_waitcnt vmcnt(" #n ")" ::: "memory")
#define LGKM0 asm volatile("s_waitcnt lgkmcnt(0)" ::: "memory")
#define PRIO1 __builtin_amdgcn_s_setprio(1)
#define PRIO0 __builtin_amdgcn_s_setprio(0)

// half-tile units: 0 = A-lo, 1 = B-lo, 2 = A-hi, 3 = B-hi
#define STAGE_UNIT(bi, kt, u) do {                                          \
    const __hip_bfloat16* gsrc;  unsigned char* ldst;                       \
    if ((u) == 0)      { gsrc = A + (size_t)(m0 + r0) * HDIM;       ldst = As[bi]; }          \
    else if ((u) == 1) { gsrc = B + (size_t)(n0 + r0) * HDIM;       ldst = Bs[bi]; }          \
    else if ((u) == 2) { gsrc = A + (size_t)(m0 + 128 + r0) * HDIM; ldst = As[bi] + 16384; }  \
    else               { gsrc = B + (size_t)(n0 + 128 + r0) * HDIM; ldst = Bs[bi] + 16384; }  \
    gsrc += (size_t)(kt) * 64 + cst * 8;                                    \
    gload_lds16(gsrc, ldst + t * 16);                                       \
    gload_lds16(gsrc + (size_t)64 * HDIM, ldst + 8192 + t * 16);            \
  } while (0)

#define RD_A(c, mh, dst) do { _Pragma("unroll") for (int mi = 0; mi < 4; ++mi) { \
    const int row = wm * 128 + (mh) * 64 + mi * 16 + lrow;                       \
    _Pragma("unroll") for (int kk = 0; kk < 2; ++kk)                             \
      dst[mi][kk] = *(const bf16x8*)(As[c] + row * 128 + (((kk * 4 + lhi) ^ rx) * 16)); \
  } } while (0)

#define RD_B(c, nh, dst) do { _Pragma("unroll") for (int ni = 0; ni < 2; ++ni) { \
    const int row = wn * 64 + (nh) * 32 + ni * 16 + lrow;                        \
    _Pragma("unroll") for (int kk = 0; kk < 2; ++kk)                             \
      dst[ni][kk] = *(const bf16x8*)(Bs[c] + row * 128 + (((kk * 4 + lhi) ^ rx) * 16)); \
  } } while (0)

#define MFMA16(AF, BF, MB, NB) do { _Pragma("unroll") for (int kk = 0; kk < 2; ++kk) \
    _Pragma("unroll") for (int mi = 0; mi < 4; ++mi)                                 \
      _Pragma("unroll") for (int ni = 0; ni < 2; ++ni)                               \
        acc[(MB) + mi][(NB) + ni] = __builtin_amdgcn_mfma_f32_16x16x32_bf16(         \
            AF[mi][kk], BF[ni][kk], acc[(MB) + mi][(NB) + ni], 0, 0, 0);             \
  } while (0)

#define ITER(j, SH123, SH4, VMSTMT) do {                                     \
    const int c_ = (j) & 1, n_ = c_ ^ 1;                                     \
    /* P1: quadrant (0,0); stage T(j+1).A-hi */                              \
    RD_A(c_, 0, afr0); RD_B(c_, 0, bfr0);                                    \
    if (SH123) STAGE_UNIT(n_, (j) + 1, 2);                                   \
    SCHED0;                                                                  \
    PRIO1; MFMA16(afr0, bfr0, 0, 0); PRIO0;                                  \
    /* P2: quadrant (1,0); stage T(j+1).B-hi */                              \
    RD_A(c_, 1, afr1);                                                       \
    if (SH123) STAGE_UNIT(n_, (j) + 1, 3);                                   \
    SCHED0;                                                                  \
    PRIO1; MFMA16(afr1, bfr0, 4, 0); PRIO0;                                  \
    /* P3: quadrant (1,1) */                                                 \
    RD_B(c_, 1, bfr1);                                                       \
    SCHED0;                                                                  \
    PRIO1; MFMA16(afr1, bfr1, 4, 2); PRIO0;                                  \
    LGKM0; SBAR;  /* all reads of buf c_ complete chip-wide */               \
    /* P4: quadrant (0,1); stage T(j+2).A-lo,B-lo into freed buf c_ */       \
    if (SH4) { STAGE_UNIT(c_, (j) + 2, 0); STAGE_UNIT(c_, (j) + 2, 1); }     \
    SCHED0;                                                                  \
    PRIO1; MFMA16(afr0, bfr1, 0, 2); PRIO0;                                  \
    VMSTMT; SBAR;                                                            \
  } while (0)

__global__ __launch_bounds__(512, 1) void gemm_bf16_kernel(
    const __hip_bfloat16* __restrict__ A,   // y_dq [8192][4096]
    const __hip_bfloat16* __restrict__ B,   // w_dq^T [4096][4096] (n-major)
    float* __restrict__ out) {              // [8192][4096]
  __shared__ __align__(16) unsigned char As[2][32768];
  __shared__ __align__(16) unsigned char Bs[2][32768];

  // XCD-aware swizzle: grid 512 = 32m x 16n tiles; XCD x gets an 8x8 sub-grid.
  const int bid = blockIdx.x;
  const int x = bid & 7, sub = bid >> 3;
  const int mtile = (x >> 1) * 8 + (sub & 7);
  const int ntile = (x & 1) * 8 + (sub >> 3);
  const int m0 = mtile * 256, n0 = ntile * 256;

  const int t = threadIdx.x;
  const int l = t & 63, wid = t >> 6;
  const int wm = wid >> 2, wn = wid & 3;    // 2x4 waves, 128x64 each
  const int lrow = l & 15, lhi = l >> 4;
  const int rx = lrow & 7;

  const int r0 = t >> 3;                    // staging row (0..63)
  const int cst = (t & 7) ^ (r0 & 7);       // pre-swizzled source chunk

  f32x4 acc[8][4];
#pragma unroll
  for (int a = 0; a < 8; ++a)
#pragma unroll
    for (int b = 0; b < 4; ++b) acc[a][b] = (f32x4){0.f, 0.f, 0.f, 0.f};
  bf16x8 afr0[4][2], afr1[4][2], bfr0[2][2], bfr1[2][2];

  // prologue: T0 all 4 units + T1.u0,u1; vmcnt(4) -> T0 landed, T1.u0,u1 fly
  STAGE_UNIT(0, 0, 0); STAGE_UNIT(0, 0, 1); STAGE_UNIT(0, 0, 2); STAGE_UNIT(0, 0, 3);
  STAGE_UNIT(1, 1, 0); STAGE_UNIT(1, 1, 1);
  VMW(4);
  SBAR;

  for (int j = 0; j <= NKT - 3; ++j) ITER(j, 1, 1, VMW(4));
  ITER(NKT - 2, 1, 0, VMW(0));   // drain: all of T(NKT-1) landed
  ITER(NKT - 1, 0, 0, (void)0);

  // epilogue: C row = lhi*4+r (m), col = lrow (n)
#pragma unroll
  for (int mi = 0; mi < 8; ++mi)
#pragma unroll
    for (int r = 0; r < 4; ++r) {
      const int grow = m0 + wm * 128 + mi * 16 + lhi * 4 + r;
      float* orow = out + (size_t)grow * HDIM + n0 + wn * 64 + lrow;
#pragma unroll
      for (int ni = 0; ni < 4; ++ni) orow[ni * 16] = acc[mi][ni][r];
    }
}

// ---------------------------------------------------------------------------
extern "C" void kernel_launch(void* const* d_in, const int* in_sizes, int n_in,
                              void* d_out, int out_size, void* d_ws, size_t ws_size,
                              hipStream_t stream) {
  const float* x = (const float*)d_in[0];    // [8192][8192]
  const float* wq = (const float*)d_in[1];   // [4096][4096]
  const float* wsc = (const float*)d_in[2];  // [32][32]
  float* out = (float*)d_out;                // [8192][4096]

  unsigned short* yb = (unsigned short*)d_ws;                   // 64 MiB bf16 y_dq
  unsigned short* wt = yb + (size_t)MDIM * HDIM;                // 32 MiB bf16 w_dq^T

  silu_quant_kernel<<<MDIM, 256, 0, stream>>>(x, yb);
  wconv_kernel<<<(HDIM / 64) * (HDIM / 64), 256, 0, stream>>>(wq, wsc, wt);
  gemm_bf16_kernel<<<(MDIM / 256) * (HDIM / 256), 512, 0, stream>>>(
      (const __hip_bfloat16*)yb, (const __hip_bfloat16*)wt, out);
}